// Round 1
// baseline (1538.900 us; speedup 1.0000x reference)
//
#include <hip/hip_runtime.h>

// Shapes (fixed by the problem)
#define BB 128      // pools
#define CC 16384    // cards
#define EE 64       // embed dims
#define MM 128      // metapath dims

typedef __bf16 bf16;
typedef bf16  bf16x8  __attribute__((ext_vector_type(8)));
typedef float floatx4 __attribute__((ext_vector_type(4)));

// ---------------------------------------------------------------------------
// k_cvt_bp: batch_pools fp32 [128][16384] -> bf16 [128][16384]
// 2M elements, 8 per thread, 1024 blocks x 256 threads.
// ---------------------------------------------------------------------------
__global__ __launch_bounds__(256) void k_cvt_bp(const float* __restrict__ bp,
                                                bf16* __restrict__ bpb) {
    int i = (blockIdx.x * 256 + threadIdx.x) * 8;
    floatx4 a = *(const floatx4*)(bp + i);
    floatx4 b = *(const floatx4*)(bp + i + 4);
    bf16x8 o;
    o[0] = (bf16)a[0]; o[1] = (bf16)a[1]; o[2] = (bf16)a[2]; o[3] = (bf16)a[3];
    o[4] = (bf16)b[0]; o[5] = (bf16)b[1]; o[6] = (bf16)b[2]; o[7] = (bf16)b[3];
    *(bf16x8*)(bpb + i) = o;
}

// ---------------------------------------------------------------------------
// k_xt: X[c][m] = sum_e ce[c][e] * kern[e][m], stored TRANSPOSED as
// Xt[m][c] in bf16 so the final GEMM's B-fragments are contiguous.
// Grid: 256 blocks, each handles a 64-wide c-tile (all 128 m).
// ---------------------------------------------------------------------------
__global__ __launch_bounds__(256) void k_xt(const float* __restrict__ ce,
                                            const float* __restrict__ kern,
                                            bf16* __restrict__ xt) {
    __shared__ float sk[EE * MM];   // kern [e][m], 32 KB
    __shared__ float sc[EE * 64];   // ce tile transposed [e][c_local], 16 KB
    int t  = threadIdx.x;
    int c0 = blockIdx.x * 64;

    // stage kern: 8192 floats = 2048 float4, 8 per thread
#pragma unroll
    for (int i = 0; i < 8; ++i) {
        int idx = (t + i * 256) * 4;
        *(floatx4*)(sk + idx) = *(const floatx4*)(kern + idx);
    }
    // stage ce tile transposed: ce[c0+row][e] -> sc[e*64 + row]
    {
        int row = t >> 2;          // 0..63 (c_local)
        int e0  = (t & 3) * 16;    // 0,16,32,48
        const float* src = ce + (size_t)(c0 + row) * EE + e0;
        floatx4 v0 = *(const floatx4*)(src);
        floatx4 v1 = *(const floatx4*)(src + 4);
        floatx4 v2 = *(const floatx4*)(src + 8);
        floatx4 v3 = *(const floatx4*)(src + 12);
#pragma unroll
        for (int j = 0; j < 4; ++j) {
            sc[(e0 + j)      * 64 + row] = v0[j];
            sc[(e0 + 4 + j)  * 64 + row] = v1[j];
            sc[(e0 + 8 + j)  * 64 + row] = v2[j];
            sc[(e0 + 12 + j) * 64 + row] = v3[j];
        }
    }
    __syncthreads();

    int mg = t & 31;   // m base = mg*4
    int cg = t >> 5;   // c_local base = cg*8
    float acc[4][8];
#pragma unroll
    for (int i = 0; i < 4; ++i)
#pragma unroll
        for (int j = 0; j < 8; ++j) acc[i][j] = 0.0f;

    for (int e = 0; e < EE; ++e) {
        floatx4 kv  = *(floatx4*)(sk + e * MM + mg * 4);
        floatx4 cv0 = *(floatx4*)(sc + e * 64 + cg * 8);
        floatx4 cv1 = *(floatx4*)(sc + e * 64 + cg * 8 + 4);
#pragma unroll
        for (int i = 0; i < 4; ++i) {
            acc[i][0] += kv[i] * cv0[0];
            acc[i][1] += kv[i] * cv0[1];
            acc[i][2] += kv[i] * cv0[2];
            acc[i][3] += kv[i] * cv0[3];
            acc[i][4] += kv[i] * cv1[0];
            acc[i][5] += kv[i] * cv1[1];
            acc[i][6] += kv[i] * cv1[2];
            acc[i][7] += kv[i] * cv1[3];
        }
    }
    // write Xt[m][c] as bf16, 16B per (m) row chunk
#pragma unroll
    for (int i = 0; i < 4; ++i) {
        bf16x8 o;
#pragma unroll
        for (int j = 0; j < 8; ++j) o[j] = (bf16)acc[i][j];
        *(bf16x8*)(xt + (size_t)(mg * 4 + i) * CC + c0 + cg * 8) = o;
    }
}

// ---------------------------------------------------------------------------
// k_pmm: THE hot kernel. P_part[kh][b][c] = sum_{k in slice} bp[b][k]*mp[c][k]
// NT-GEMM, bf16 MFMA 16x16x32, no LDS / no barriers: both operands are
// K-major so each lane's fragment is a contiguous 16B (A, bf16) or 32B
// (B, fp32 -> cvt) load. Grid = 128 c-tiles x 4 K-slices = 512 blocks,
// block = 4 waves, wave computes [128 b x 32 c].
// ---------------------------------------------------------------------------
__global__ __launch_bounds__(256, 2) void k_pmm(const float* __restrict__ mp,
                                                const bf16* __restrict__ bpb,
                                                bf16* __restrict__ pp) {
    const int lane  = threadIdx.x & 63;
    const int wave  = threadIdx.x >> 6;
    const int ctile = blockIdx.x & 127;
    const int kh    = blockIdx.x >> 7;
    const int r     = lane & 15;
    const int q     = lane >> 4;
    const int cbase = ctile * 128 + wave * 32;
    const int kbeg  = kh * 4096;
    const int kend  = kbeg + 4096;

    // per-lane base pointers (fragment layouts per cdna4 guide, m89-verified):
    // A[m=lane&15][k=(lane>>4)*8+j], B[k=(lane>>4)*8+j][n=lane&15]
    const float* mp0 = mp + (size_t)(cbase + r) * CC + q * 8;  // + ct*16*CC + k
    const bf16*  bp0 = bpb + (size_t)r * CC + q * 8;           // + bt*16*CC + k

    floatx4 acc[8][2];
#pragma unroll
    for (int bt = 0; bt < 8; ++bt)
#pragma unroll
        for (int ct = 0; ct < 2; ++ct) {
            floatx4 z = {0.f, 0.f, 0.f, 0.f};
            acc[bt][ct] = z;
        }

    // software prefetch of the HBM stream (mp), depth 1
    floatx4 pf00 = *(const floatx4*)(mp0 + kbeg);
    floatx4 pf01 = *(const floatx4*)(mp0 + kbeg + 4);
    floatx4 pf10 = *(const floatx4*)(mp0 + (size_t)16 * CC + kbeg);
    floatx4 pf11 = *(const floatx4*)(mp0 + (size_t)16 * CC + kbeg + 4);

    for (int k0 = kbeg; k0 < kend; k0 += 32) {
        floatx4 c00 = pf00, c01 = pf01, c10 = pf10, c11 = pf11;
        int kn = k0 + 32;
        if (kn < kend) {
            pf00 = *(const floatx4*)(mp0 + kn);
            pf01 = *(const floatx4*)(mp0 + kn + 4);
            pf10 = *(const floatx4*)(mp0 + (size_t)16 * CC + kn);
            pf11 = *(const floatx4*)(mp0 + (size_t)16 * CC + kn + 4);
        }
        bf16x8 b0, b1;
#pragma unroll
        for (int j = 0; j < 4; ++j) {
            b0[j]     = (bf16)c00[j];
            b0[4 + j] = (bf16)c01[j];
            b1[j]     = (bf16)c10[j];
            b1[4 + j] = (bf16)c11[j];
        }
        const bf16* ap = bp0 + k0;
#pragma unroll
        for (int bt = 0; bt < 8; ++bt) {
            bf16x8 a = *(const bf16x8*)(ap + (size_t)bt * 16 * CC);
            acc[bt][0] = __builtin_amdgcn_mfma_f32_16x16x32_bf16(a, b0, acc[bt][0], 0, 0, 0);
            acc[bt][1] = __builtin_amdgcn_mfma_f32_16x16x32_bf16(a, b1, acc[bt][1], 0, 0, 0);
        }
    }

    // store partial P plane (bf16). D layout: row=(lane>>4)*4+reg, col=lane&15
    bf16* op = pp + (size_t)kh * BB * CC;
#pragma unroll
    for (int bt = 0; bt < 8; ++bt)
#pragma unroll
        for (int ct = 0; ct < 2; ++ct)
#pragma unroll
            for (int rr = 0; rr < 4; ++rr) {
                int b = bt * 16 + q * 4 + rr;
                int c = cbase + ct * 16 + r;
                op[(size_t)b * CC + c] = (bf16)acc[bt][ct][rr];
            }
}

// ---------------------------------------------------------------------------
// k_out1: out partials. part[cb][b][m] = sum_{kh} sum_{c in cb-range}
//         P_part[kh][b][c] * Xt[m][c].  128 blocks (c-split), MFMA,
//         per-block private output plane (no atomics).
// ---------------------------------------------------------------------------
__global__ __launch_bounds__(256) void k_out1(const bf16* __restrict__ pp,
                                              const bf16* __restrict__ xt,
                                              float* __restrict__ part) {
    const int lane = threadIdx.x & 63;
    const int wave = threadIdx.x >> 6;
    const int r    = lane & 15;
    const int q    = lane >> 4;
    const int cb   = blockIdx.x;       // c-range [cb*128, cb*128+128)
    const int m0   = wave * 32;

    floatx4 acc[8][2];
#pragma unroll
    for (int bt = 0; bt < 8; ++bt)
#pragma unroll
        for (int ct = 0; ct < 2; ++ct) {
            floatx4 z = {0.f, 0.f, 0.f, 0.f};
            acc[bt][ct] = z;
        }

    for (int kh = 0; kh < 4; ++kh) {
        const bf16* pbase = pp + (size_t)kh * BB * CC + (size_t)r * CC + cb * 128 + q * 8;
        const bf16* xbase = xt + (size_t)(m0 + r) * CC + cb * 128 + q * 8;
#pragma unroll
        for (int k0 = 0; k0 < 128; k0 += 32) {
            bf16x8 b0 = *(const bf16x8*)(xbase + k0);
            bf16x8 b1 = *(const bf16x8*)(xbase + (size_t)16 * CC + k0);
#pragma unroll
            for (int bt = 0; bt < 8; ++bt) {
                bf16x8 a = *(const bf16x8*)(pbase + (size_t)bt * 16 * CC + k0);
                acc[bt][0] = __builtin_amdgcn_mfma_f32_16x16x32_bf16(a, b0, acc[bt][0], 0, 0, 0);
                acc[bt][1] = __builtin_amdgcn_mfma_f32_16x16x32_bf16(a, b1, acc[bt][1], 0, 0, 0);
            }
        }
    }

    float* op = part + (size_t)cb * (BB * MM);
#pragma unroll
    for (int bt = 0; bt < 8; ++bt)
#pragma unroll
        for (int ct = 0; ct < 2; ++ct)
#pragma unroll
            for (int rr = 0; rr < 4; ++rr) {
                int b = bt * 16 + q * 4 + rr;
                int m = m0 + ct * 16 + r;
                op[(size_t)b * MM + m] = acc[bt][ct][rr];
            }
}

// ---------------------------------------------------------------------------
// k_out2: reduce 128 partial planes -> out[128][128] fp32, coalesced.
// ---------------------------------------------------------------------------
__global__ __launch_bounds__(256) void k_out2(const float* __restrict__ part,
                                              float* __restrict__ out) {
    int i = blockIdx.x * 256 + threadIdx.x;  // 64 blocks -> 16384 threads
    float s = 0.0f;
    for (int j = 0; j < 128; ++j) s += part[(size_t)j * (BB * MM) + i];
    out[i] = s;
}

// ---------------------------------------------------------------------------
extern "C" void kernel_launch(void* const* d_in, const int* in_sizes, int n_in,
                              void* d_out, int out_size, void* d_ws, size_t ws_size,
                              hipStream_t stream) {
    const float* bp   = (const float*)d_in[0];  // batch_pools  [128][16384]
    const float* mp   = (const float*)d_in[1];  // metapath     [16384][16384]
    const float* ce   = (const float*)d_in[2];  // card_embeddings [16384][64]
    const float* kern = (const float*)d_in[3];  // kernel       [64][128]
    float* out = (float*)d_out;

    char* ws = (char*)d_ws;
    bf16*  bpb  = (bf16*)ws;                      //  4 MB: bp in bf16
    bf16*  xt   = (bf16*)(ws + (4u << 20));       //  4 MB: Xt[m][c] bf16
    bf16*  pp   = (bf16*)(ws + (8u << 20));       // 16 MB: P partials [4][128][16384]
    float* part = (float*)(ws + (24u << 20));     //  8 MB: out partials [128][128][128]

    k_cvt_bp<<<1024, 256, 0, stream>>>(bp, bpb);
    k_xt   <<< 256, 256, 0, stream>>>(ce, kern, xt);
    k_pmm  <<< 512, 256, 0, stream>>>(mp, bpb, pp);
    k_out1 <<< 128, 256, 0, stream>>>(pp, xt, part);
    k_out2 <<<  64, 256, 0, stream>>>(part, out);
}